// Round 1
// 234.658 us; speedup vs baseline: 1.0416x; 1.0416x over previous
//
#include <hip/hip_runtime.h>
#include <stdint.h>

// BinaryLinearWscales: out[m,n] = wscale[n] * (x @ sign(W)^T)[m,n] + wbias[n] * rowsum(x)[m]
// M = B*S = 4096, N = DOUT = 4096, K = DIN = 4096.
// Round 6: 256x256 8-phase i8 GEMM (HK-style schedule in plain HIP).
//   - BK=128 i8 bytes/row, K-half-split LDS slots of 16 KiB: [2 buf][2 khalf] x {A,B}
//   - 8 waves (2M x 4N), per-wave 128x64 out, acc[2][4][4] of mfma_i32_16x16x64_i8
//   - per phase: {ds_read subtile || stage 1 half-tile} -> barrier -> lgkmcnt(0)
//                -> setprio(1) -> 16 MFMA -> setprio(0) -> [vmcnt(4) at tile edge] -> barrier
//   - stage schedule per tile t: j0:Ak1(t+1) j1:Bk1(t+1) j2:Ak0(t+2) j3:Bk0(t+2)
//     (each target slot's previous occupant was last read >=1 barrier earlier)
//   - counted vmcnt(4) at tile boundaries (2 half-tiles stay in flight); tail drains to 0.
//   - LDS swizzle: phys16B-chunk = chunk ^ ((row ^ row>>2)&3) within 64-B half-rows
//     -> exact 2-way (free) bank aliasing; staging pre-swizzles the GLOBAL source
//     (linear LDS dest, rule 21), read applies same involution.

#define MDIM 4096
#define NDIM 4096
#define KDIM 4096

typedef int int4v __attribute__((ext_vector_type(4)));

__device__ __forceinline__ int pack4_rn(float a, float b, float c, float d, float inv) {
  int ia = __float2int_rn(a * inv) & 0xff;
  int ib = __float2int_rn(b * inv) & 0xff;
  int ic = __float2int_rn(c * inv) & 0xff;
  int id = __float2int_rn(d * inv) & 0xff;
  return ia | (ib << 8) | (ic << 16) | (id << 24);
}

__device__ __forceinline__ int sgn8(float v) {
  return (v > 0.f) ? 1 : ((v < 0.f) ? 0xff : 0);
}

// ---------------- fused prep (UNCHANGED this round: isolates gemm delta) ----------------
__global__ __launch_bounds__(256) void prep_kernel(
    const float* __restrict__ x, const float* __restrict__ w,
    char* __restrict__ xq, char* __restrict__ wsg,
    float* __restrict__ xscale, float* __restrict__ sumx) {
  const int b = blockIdx.x;
  const int tid = threadIdx.x;
  if (b < MDIM) {
    const int row = b;
    const float4* xr = (const float4*)(x + (size_t)row * KDIM);
    float4 v[4];
    float s = 0.f, amax = 0.f;
#pragma unroll
    for (int u = 0; u < 4; ++u) {
      v[u] = xr[u * 256 + tid];
      s += v[u].x + v[u].y + v[u].z + v[u].w;
      amax = fmaxf(amax, fmaxf(fmaxf(fabsf(v[u].x), fabsf(v[u].y)),
                               fmaxf(fabsf(v[u].z), fabsf(v[u].w))));
    }
#pragma unroll
    for (int off = 32; off > 0; off >>= 1) {
      s += __shfl_down(s, off, 64);
      amax = fmaxf(amax, __shfl_down(amax, off, 64));
    }
    __shared__ float rs[4], rm[4], bcast;
    if ((tid & 63) == 0) { rs[tid >> 6] = s; rm[tid >> 6] = amax; }
    __syncthreads();
    if (tid == 0) {
      sumx[row] = rs[0] + rs[1] + rs[2] + rs[3];
      float mt = fmaxf(fmaxf(rm[0], rm[1]), fmaxf(rm[2], rm[3]));
      xscale[row] = mt * (1.f / 127.f);
      bcast = (mt > 0.f) ? 127.f / mt : 0.f;
    }
    __syncthreads();
    const float inv = bcast;
    int* xo = (int*)(xq + (size_t)row * KDIM);
#pragma unroll
    for (int u = 0; u < 4; ++u)
      xo[u * 256 + tid] = pack4_rn(v[u].x, v[u].y, v[u].z, v[u].w, inv);
  } else {
    const size_t base = (size_t)(b - MDIM) * (256 * 4);
    const float4* wr = (const float4*)w;
    int* wo = (int*)wsg;
#pragma unroll
    for (int u = 0; u < 4; ++u) {
      size_t i = base + u * 256 + tid;
      float4 v = wr[i];
      wo[i] = sgn8(v.x) | (sgn8(v.y) << 8) | (sgn8(v.z) << 16) | (sgn8(v.w) << 24);
    }
  }
}

// ---------------- 256x256 8-phase i8 GEMM ----------------
__global__ __launch_bounds__(512, 2) void gemm_bin_i8_8phase(
    const char* __restrict__ A, const char* __restrict__ Bs,
    const float* __restrict__ wscale, const float* __restrict__ wbias,
    const float* __restrict__ xscale, const float* __restrict__ sumx,
    float* __restrict__ C) {
  // A region: [0,64K) = (buf*2+kh)*16384 ; B region: [64K,128K)
  __shared__ __align__(16) char sm[131072];

  const int bm = blockIdx.x >> 4, bn = blockIdx.x & 15;
  const int tm0 = bm * 256, tn0 = bn * 256;
  const int tid = threadIdx.x;
  const int lane = tid & 63, wave = tid >> 6;
  const int quad = lane >> 4, l16 = lane & 15;
  const int wr = wave >> 2, wc = wave & 3;   // 2 x 4 wave grid

  int4v acc[2][4][4];
  const int4v zero4 = {0, 0, 0, 0};
#pragma unroll
  for (int rh = 0; rh < 2; ++rh)
#pragma unroll
    for (int i = 0; i < 4; ++i)
#pragma unroll
      for (int j = 0; j < 4; ++j) acc[rh][i][j] = zero4;

  int4v bf[4];  // B frags, loaded at rh=0, reused at rh=1

  // ds_read offsets (swizzled). row in [0,256), 64-B half-rows, 4 x 16-B chunks.
  int aOff[2][4];
#pragma unroll
  for (int rh = 0; rh < 2; ++rh)
#pragma unroll
    for (int i = 0; i < 4; ++i) {
      int row = wr * 128 + rh * 64 + i * 16 + l16;
      int sw = (row ^ (row >> 2)) & 3;
      aOff[rh][i] = row * 64 + ((quad ^ sw) & 3) * 16;
    }
  int bOff[4];
#pragma unroll
  for (int j = 0; j < 4; ++j) {
    int row = wc * 64 + j * 16 + l16;
    int sw = (row ^ (row >> 2)) & 3;
    bOff[j] = 65536 + row * 64 + ((quad ^ sw) & 3) * 16;
  }

  // staging: half-tile = 256 rows x 64 B = 16 KiB = 2 rounds of 512 thr x 16 B.
  // linear LDS dest u*16 (row=u>>2, phys=u&3) <- global chunk c_log = (u&3)^sw(row)
  const int u0 = tid, u1 = tid + 512;
  const int r0 = u0 >> 2, r1 = u1 >> 2;
  const int c0 = (u0 & 3) ^ ((r0 ^ (r0 >> 2)) & 3);
  const int c1 = (u1 & 3) ^ ((r1 ^ (r1 >> 2)) & 3);
  const char* gA0 = A + (size_t)(tm0 + r0) * KDIM + c0 * 16;
  const char* gA1 = A + (size_t)(tm0 + r1) * KDIM + c1 * 16;
  const char* gB0 = Bs + (size_t)(tn0 + r0) * KDIM + c0 * 16;
  const char* gB1 = Bs + (size_t)(tn0 + r1) * KDIM + c1 * 16;
  const int ldsu0 = tid * 16, ldsu1 = 8192 + tid * 16;

#define STAGE_A(BUF, KH, KOFS)                                                    \
  do {                                                                            \
    const int base_ = ((BUF) * 2 + (KH)) * 16384;                                 \
    __builtin_amdgcn_global_load_lds(                                             \
        (const __attribute__((address_space(1))) void*)(gA0 + (KOFS)),            \
        (__attribute__((address_space(3))) void*)(sm + base_ + ldsu0), 16, 0, 0); \
    __builtin_amdgcn_global_load_lds(                                             \
        (const __attribute__((address_space(1))) void*)(gA1 + (KOFS)),            \
        (__attribute__((address_space(3))) void*)(sm + base_ + ldsu1), 16, 0, 0); \
  } while (0)

#define STAGE_B(BUF, KH, KOFS)                                                    \
  do {                                                                            \
    const int base_ = 65536 + ((BUF) * 2 + (KH)) * 16384;                         \
    __builtin_amdgcn_global_load_lds(                                             \
        (const __attribute__((address_space(1))) void*)(gB0 + (KOFS)),            \
        (__attribute__((address_space(3))) void*)(sm + base_ + ldsu0), 16, 0, 0); \
    __builtin_amdgcn_global_load_lds(                                             \
        (const __attribute__((address_space(1))) void*)(gB1 + (KOFS)),            \
        (__attribute__((address_space(3))) void*)(sm + base_ + ldsu1), 16, 0, 0); \
  } while (0)

#define BAR __builtin_amdgcn_s_barrier()
#define CK4 asm volatile("s_waitcnt vmcnt(4)\n\ts_barrier" ::: "memory")
#define CK0 asm volatile("s_waitcnt vmcnt(0)\n\ts_barrier" ::: "memory")

// phase: ds_read subtile + stage (VA_ARGS) -> barrier -> lgkm drain (pinned, rule 18)
// -> prio-boosted 16 MFMA -> end barrier (CKBAR = BAR | CK4 | CK0)
#define PHASE(BUF, KS, RH, CKBAR, ...)                                            \
  do {                                                                            \
    int4v af[4];                                                                  \
    _Pragma("unroll") for (int i_ = 0; i_ < 4; ++i_)                              \
        af[i_] = *(const int4v*)(sm + ((BUF) * 2 + (KS)) * 16384 + aOff[RH][i_]); \
    if ((RH) == 0) {                                                              \
      _Pragma("unroll") for (int j_ = 0; j_ < 4; ++j_)                            \
          bf[j_] = *(const int4v*)(sm + ((BUF) * 2 + (KS)) * 16384 + bOff[j_]);   \
    }                                                                             \
    __VA_ARGS__;                                                                  \
    __builtin_amdgcn_s_barrier();                                                 \
    asm volatile("s_waitcnt lgkmcnt(0)" ::: "memory");                            \
    __builtin_amdgcn_sched_barrier(0);                                            \
    __builtin_amdgcn_s_setprio(1);                                                \
    _Pragma("unroll") for (int i_ = 0; i_ < 4; ++i_)                              \
        _Pragma("unroll") for (int j_ = 0; j_ < 4; ++j_)                          \
            acc[RH][i_][j_] = __builtin_amdgcn_mfma_i32_16x16x64_i8(              \
                af[i_], bf[j_], acc[RH][i_][j_], 0, 0, 0);                        \
    __builtin_amdgcn_s_setprio(0);                                                \
    CKBAR;                                                                        \
  } while (0)

// one K-tile (4 phases): compute tile TAU from BUF; stage k1(TAU+1), k0(TAU+2)
#define ITER_FULL(BUF, TAU)                                                       \
  do {                                                                            \
    PHASE(BUF, 0, 0, BAR, STAGE_A((BUF) ^ 1, 1, ((TAU) + 1) * 128 + 64));         \
    PHASE(BUF, 0, 1, BAR, STAGE_B((BUF) ^ 1, 1, ((TAU) + 1) * 128 + 64));         \
    PHASE(BUF, 1, 0, BAR, STAGE_A(BUF, 0, ((TAU) + 2) * 128));                    \
    PHASE(BUF, 1, 1, CK4, STAGE_B(BUF, 0, ((TAU) + 2) * 128));                    \
  } while (0)

  // prologue: tile0 {k0,k1} + tile1 {k0}; keep last 2 half-tiles (4 loads) in flight
  STAGE_A(0, 0, 0);
  STAGE_B(0, 0, 0);
  STAGE_A(0, 1, 64);
  STAGE_B(0, 1, 64);
  STAGE_A(1, 0, 128);
  STAGE_B(1, 0, 128);
  CK4;

  // 32 K-tiles total: steady tau = 0..29, then peeled tail
#pragma unroll 1
  for (int t = 0; t < 30; t += 2) {
    ITER_FULL(0, t);
    ITER_FULL(1, t + 1);
  }
  // tau = 30 (buf 0): stage only tile31 k1; drain at end
  PHASE(0, 0, 0, BAR, STAGE_A(1, 1, 31 * 128 + 64));
  PHASE(0, 0, 1, BAR, STAGE_B(1, 1, 31 * 128 + 64));
  PHASE(0, 1, 0, BAR, (void)0);
  PHASE(0, 1, 1, CK0, (void)0);
  // tau = 31 (buf 1): compute only
  PHASE(1, 0, 0, BAR, (void)0);
  PHASE(1, 0, 1, BAR, (void)0);
  PHASE(1, 1, 0, BAR, (void)0);
  PHASE(1, 1, 1, BAR, (void)0);

#undef ITER_FULL
#undef PHASE
#undef BAR
#undef CK4
#undef CK0
#undef STAGE_A
#undef STAGE_B

  // epilogue: C[m,n] = wscale[n]*xscale[m]*acc + wbias[n]*sumx[m]
  // D frag layout (verified): row = quad*4 + reg, col = l16
  float wsv[4], wbv[4];
#pragma unroll
  for (int j = 0; j < 4; ++j) {
    int n = tn0 + wc * 64 + j * 16 + l16;
    wsv[j] = wscale[n];
    wbv[j] = wbias[n];
  }
#pragma unroll
  for (int rh = 0; rh < 2; ++rh) {
#pragma unroll
    for (int i = 0; i < 4; ++i) {
#pragma unroll
      for (int r = 0; r < 4; ++r) {
        int m = tm0 + wr * 128 + rh * 64 + i * 16 + quad * 4 + r;
        float xs = xscale[m];
        float sx = sumx[m];
        float* crow = C + (size_t)m * NDIM + tn0 + wc * 64 + l16;
#pragma unroll
        for (int j = 0; j < 4; ++j)
          crow[j * 16] = wsv[j] * xs * (float)acc[rh][i][j][r] + wbv[j] * sx;
      }
    }
  }
}

extern "C" void kernel_launch(void* const* d_in, const int* in_sizes, int n_in,
                              void* d_out, int out_size, void* d_ws, size_t ws_size,
                              hipStream_t stream) {
  const float* x      = (const float*)d_in[0];
  const float* weight = (const float*)d_in[1];
  const float* wscale = (const float*)d_in[2];
  const float* wbias  = (const float*)d_in[3];
  float* out = (float*)d_out;

  char* xq  = (char*)d_ws;
  char* wsg = xq + (size_t)MDIM * KDIM;
  float* xscale = (float*)(wsg + (size_t)NDIM * KDIM);
  float* sumx   = xscale + MDIM;

  prep_kernel<<<MDIM + (NDIM * KDIM) / (16 * 256), 256, 0, stream>>>(
      x, weight, xq, wsg, xscale, sumx);
  gemm_bin_i8_8phase<<<(MDIM / 256) * (NDIM / 256), 512, 0, stream>>>(
      xq, wsg, wscale, wbias, xscale, sumx, out);
}